// Round 7
// baseline (145.446 us; speedup 1.0000x reference)
//
#include <hip/hip_runtime.h>
#include <math.h>

#define PTS_PER_BLOCK 9
#define NPTS_PER_WAVE 3
#define WAVES_PER_BLOCK 3

typedef _Float16 h8 __attribute__((ext_vector_type(8)));
typedef _Float16 h2 __attribute__((ext_vector_type(2)));
typedef __fp16   fp16x2 __attribute__((ext_vector_type(2)));
typedef float    f4 __attribute__((ext_vector_type(4)));
typedef unsigned int uint32;

// cfg constants
#define CSE_C 0.5f
#define CLE_C 0.00574f
#define DCOEF (CSE_C - CLE_C)          // 0.49426
#define KCOEF (1.0f - CSE_C + CLE_C)   // 0.50574

__device__ __forceinline__ float tanh_fast(float xx) {
    float e = __expf(2.0f * xx);
    float r = __builtin_amdgcn_rcpf(e + 1.0f);
    return fmaf(-2.0f, r, 1.0f);
}
__device__ __forceinline__ unsigned short f2h(float a) {
    union { _Float16 h; unsigned short u; } ua; ua.h = (_Float16)a; return ua.u;
}
__device__ __forceinline__ h2 pkrtz(float a, float b) {
    union { fp16x2 f; h2 h; } x; x.f = __builtin_amdgcn_cvt_pkrtz(a, b); return x.h;
}
__device__ __forceinline__ uint32 pk2h(float a, float b) {
    union { h2 h; uint32 u; } x; x.h = pkrtz(a, b); return x.u;
}
__device__ __forceinline__ h8 h8_from2x2(uint2 lo, uint2 hi) {
    union { uint32 u[4]; h8 v; } x;
    x.u[0] = lo.x; x.u[1] = lo.y; x.u[2] = hi.x; x.u[3] = hi.y;
    return x.v;
}
__device__ __forceinline__ h8 h8_from4(uint32 a, uint32 b, uint32 c, uint32 d) {
    union { uint32 u[4]; h8 v; } x; x.u[0] = a; x.u[1] = b; x.u[2] = c; x.u[3] = d;
    return x.v;
}

// ---------------------------------------------------------------------------
// Prep: Wh (4,128,128 f32) -> A-fragment-ordered f16 W^T tiles, [L][jo][kt]
// A-frag (16x16x32 f16): lane holds row m=lane&15, k=(lane>>4)*8+e.
//   Wp[ ((L*8+jo)*4+kt)*256 + lane*4 + d ] packs (k=kt*32+(lane>>4)*8+2d, k+1)
// value = W^T[m,k] = Wh[L][k][jout=jo*16+m]
// ---------------------------------------------------------------------------
extern "C" __global__ __launch_bounds__(256)
void pinn_prep(const float* __restrict__ Wh, uint32* __restrict__ Wp)
{
    int gid  = blockIdx.x * 256 + threadIdx.x;       // 0..32767
    int d    = gid & 3;
    int lane = (gid >> 2) & 63;
    int kt   = (gid >> 8) & 3;
    int jo   = (gid >> 10) & 7;
    int L    = gid >> 13;
    int j    = kt * 32 + (lane >> 4) * 8 + 2 * d;
    int jout = jo * 16 + (lane & 15);
    float w0 = Wh[(L * 128 + j) * 128 + jout];
    float w1 = Wh[(L * 128 + j + 1) * 128 + jout];
    Wp[gid] = pk2h(w0, w1);
}

// ---------------------------------------------------------------------------
// Main: barrier-free. One wave = 3 points = 6 branch-points (bp), 5 channels:
//   ch: 0=value 1=d/dt 2=d/dx0 3=d/dx1 4=laplacian
// H rows [32][136] f16 per wave; column bytes XOR-swizzled by row parity
// (colbyte ^= (row&1)<<3) so fragment reads are 2x ds_read_b64 at 4-way
// instead of 1x b128 at 8-way bank conflict. W streamed from L2, 3-deep
// prefetch. Native v_sin/v_cos (revolutions) in the embedding.
// ---------------------------------------------------------------------------
extern "C" __global__ __launch_bounds__(192, 4)
void pinn_mfma(const float* __restrict__ x, const float* __restrict__ t,
               const float* __restrict__ B, const uint32* __restrict__ Wp,
               const float* __restrict__ bh, const float* __restrict__ Wout,
               const float* __restrict__ bout, float* __restrict__ out, int npts)
{
    __shared__ __align__(16) unsigned short H[WAVES_PER_BLOCK][32][136]; // 26112 B

    const int tid  = threadIdx.x;
    const int lane = tid & 63;
    const int wv   = tid >> 6;
    const int c    = lane & 15;
    const int g    = lane >> 4;
    const int base_pt = blockIdx.x * PTS_PER_BLOCK + wv * NPTS_PER_WAVE;

    unsigned char* Hc = (unsigned char*)&H[wv][0][0];

    // swizzled per-lane byte bases
    const int par   = c & 1;
    const int e0    = lane * 2;                      // embed, even rows
    const int e1    = e0 ^ 8;                        // embed, odd rows
    const int pb0   = lane * 4;                      // phase B, even rows
    const int pb1   = pb0 ^ 8;                       // phase B, odd rows
    const int wb0   = c * 272 + ((g * 8) ^ (par << 3));   // phase A write base
    const int fb_lo = c * 272 + g * 16 + (par << 3);      // frag read, lo 8B
    const int fb_hi = fb_lo ^ 8;                          // frag read, hi 8B

    // ---------------- embedding (writes layer-0 H) ----------------
    {
        const float TWO_PI = 6.28318530717958647692f;
        const float Br0 = B[lane], Br1 = B[64 + lane], Br2 = B[128 + lane];
        const float b0 = TWO_PI * Br0, b1 = TWO_PI * Br1, b2 = TWO_PI * Br2;
        const float bsq = fmaf(b0, b0, b1 * b1);
        #pragma unroll
        for (int pl = 0; pl < 3; ++pl) {
            int pt = base_pt + pl; if (pt > npts - 1) pt = npts - 1;
            const float2 xx = *(const float2*)&x[2 * pt];
            const float tt = t[pt];
            const float uc = fmaf(xx.y, Br1, tt * Br2);
            const float ux = xx.x * Br0;
            #pragma unroll
            for (int mir = 0; mir < 2; ++mir) {
                float u = mir ? (uc - ux) : (uc + ux);
                float r = u - floorf(u);
                float sf = __builtin_amdgcn_sinf(r);   // sin(2*pi*u)
                float cf = __builtin_amdgcn_cosf(r);   // cos(2*pi*u)
                const int b  = pl * 2 + mir;
                const int rs = (b < 3) ? 5 * b : 16 + 5 * (b - 3);
                // values per channel: sin half (col=lane), cos half (col=64+lane)
                const float sv[5] = { sf,  cf * b2,  cf * b0,  cf * b1, -sf * bsq };
                const float cv[5] = { cf, -sf * b2, -sf * b0, -sf * b1, -cf * bsq };
                #pragma unroll
                for (int ch = 0; ch < 5; ++ch) {
                    const int row = rs + ch;
                    const int eb  = (row & 1) ? e1 : e0;
                    *(unsigned short*)(Hc + eb + row * 272)       = f2h(sv[ch]);
                    *(unsigned short*)(Hc + eb + row * 272 + 128) = f2h(cv[ch]);
                }
            }
        }
    }
    asm volatile("s_waitcnt lgkmcnt(0)" ::: "memory");

    // ---------------- hidden layers ----------------
    for (int L = 0; L < 4; ++L) {
        // B-fragments: row = ct*16+c, cols kt*32+g*8..+7 (2x b64, swizzled)
        h8 bf[2][4];
        #pragma unroll
        for (int ct = 0; ct < 2; ++ct)
            #pragma unroll
            for (int kt = 0; kt < 4; ++kt) {
                uint2 lo = *(const uint2*)(Hc + fb_lo + ct * 4352 + kt * 64);
                uint2 hi = *(const uint2*)(Hc + fb_hi + ct * 4352 + kt * 64);
                bf[ct][kt] = h8_from2x2(lo, hi);
            }

        const uint4* WL = (const uint4*)Wp + (size_t)L * 2048;   // layer base

        // W tiles triple-buffered (static idx under full unroll)
        uint4 wt[3][4];
        #pragma unroll
        for (int kt = 0; kt < 4; ++kt) wt[0][kt] = WL[kt * 64 + lane];
        #pragma unroll
        for (int kt = 0; kt < 4; ++kt) wt[1][kt] = WL[(4 + kt) * 64 + lane];

        #pragma unroll
        for (int jo = 0; jo < 8; ++jo) {
            if (jo < 6) {
                #pragma unroll
                for (int kt = 0; kt < 4; ++kt)
                    wt[(jo + 2) % 3][kt] = WL[((jo + 2) * 4 + kt) * 64 + lane];
            }
            f4 a0 = {0.f, 0.f, 0.f, 0.f}, a1 = {0.f, 0.f, 0.f, 0.f};
            #pragma unroll
            for (int kt = 0; kt < 4; ++kt) {
                union { uint4 u; h8 v; } af;
                af.u = wt[jo % 3][kt];
                a0 = __builtin_amdgcn_mfma_f32_16x16x32_f16(af.v, bf[0][kt], a0, 0, 0, 0);
                a1 = __builtin_amdgcn_mfma_f32_16x16x32_f16(af.v, bf[1][kt], a1, 0, 0, 0);
            }
            // phase A: raw pre-activations (C layout: row=jo*16+g*4+r, col=c)
            union { h2 h[2]; uint2 u; } w0, w1;
            w0.h[0] = pkrtz(a0[0], a0[1]); w0.h[1] = pkrtz(a0[2], a0[3]);
            w1.h[0] = pkrtz(a1[0], a1[1]); w1.h[1] = pkrtz(a1[2], a1[3]);
            *(uint2*)(Hc + wb0 + jo * 32)        = w0.u;
            *(uint2*)(Hc + wb0 + 4352 + jo * 32) = w1.u;
        }
        asm volatile("s_waitcnt lgkmcnt(0)" ::: "memory");

        // phase B: lane-private j-columns (j = 2*lane, 2*lane+1), packed f16.
        // Bias (value channel only) applied here.
        {
            const float2 bj = *(const float2*)&bh[L * 128 + 2 * lane];
            const h2 bias2 = pkrtz(bj.x, bj.y);
            const h2 m2 = {(_Float16)(-2.0f), (_Float16)(-2.0f)};
            #pragma unroll
            for (int b = 0; b < 6; ++b) {
                const int rs = (b < 3) ? 5 * b : 16 + 5 * (b - 3);
                #define PB(k) (Hc + (((rs + (k)) & 1) ? pb1 : pb0) + (rs + (k)) * 272)
                h2 vp = *(const h2*)PB(0);
                h2 tp = *(const h2*)PB(1);
                h2 pp = *(const h2*)PB(2);
                h2 qp = *(const h2*)PB(3);
                h2 Lp = *(const h2*)PB(4);
                vp = vp + bias2;
                float y0 = tanh_fast((float)vp[0]);
                float y1 = tanh_fast((float)vp[1]);
                h2 yp = pkrtz(y0, y1);
                h2 sp = pkrtz(fmaf(-y0, y0, 1.f), fmaf(-y1, y1, 1.f));
                h2 qq = __builtin_elementwise_fma(pp, pp, qp * qp);
                h2 Ln = sp * __builtin_elementwise_fma(yp * m2, qq, Lp);
                *(h2*)PB(0) = yp;
                *(h2*)PB(1) = sp * tp;
                *(h2*)PB(2) = sp * pp;
                *(h2*)PB(3) = sp * qp;
                *(h2*)PB(4) = Ln;
                #undef PB
            }
        }
        asm volatile("s_waitcnt lgkmcnt(0)" ::: "memory");
    }

    // ---------------- output layer via MFMA + residual ----------------
    {
        // A = Wout^T (2x128, rows 2..15 zeroed), built in-register
        h8 afo[4];
        const int   mc  = c & 1;
        const float sel = (c < 2) ? 1.0f : 0.0f;
        #pragma unroll
        for (int kt = 0; kt < 4; ++kt) {
            uint32 u[4];
            #pragma unroll
            for (int d = 0; d < 4; ++d) {
                int k = kt * 32 + g * 8 + 2 * d;
                float w0 = Wout[k * 2 + mc] * sel;
                float w1 = Wout[(k + 1) * 2 + mc] * sel;
                u[d] = pk2h(w0, w1);
            }
            afo[kt] = h8_from4(u[0], u[1], u[2], u[3]);
        }
        // B = final H (same swizzled fragment pattern)
        h8 bfo[2][4];
        #pragma unroll
        for (int ct = 0; ct < 2; ++ct)
            #pragma unroll
            for (int kt = 0; kt < 4; ++kt) {
                uint2 lo = *(const uint2*)(Hc + fb_lo + ct * 4352 + kt * 64);
                uint2 hi = *(const uint2*)(Hc + fb_hi + ct * 4352 + kt * 64);
                bfo[ct][kt] = h8_from2x2(lo, hi);
            }

        f4 ac0 = {0.f, 0.f, 0.f, 0.f}, ac1 = {0.f, 0.f, 0.f, 0.f};
        #pragma unroll
        for (int kt = 0; kt < 4; ++kt) {
            ac0 = __builtin_amdgcn_mfma_f32_16x16x32_f16(afo[kt], bfo[0][kt], ac0, 0, 0, 0);
            ac1 = __builtin_amdgcn_mfma_f32_16x16x32_f16(afo[kt], bfo[1][kt], ac1, 0, 0, 0);
        }
        // g==0 lanes hold rows 0 (=o0) and 1 (=o1) for col c; stash to LDS
        float* S = (float*)Hc;        // 256 B scratch, H no longer needed
        if (g == 0) {
            f4 pack = {ac0[0], ac0[1], ac1[0], ac1[1]};   // o0ct0,o1ct0,o0ct1,o1ct1
            *(f4*)&S[c * 4] = pack;
        }
        asm volatile("s_waitcnt lgkmcnt(0)" ::: "memory");

        if (lane < 3) {
            int pt = base_pt + lane;
            if (pt < npts) {
                float bo0 = bout[0], bo1 = bout[1];
                float ph = 0.f, cv = 0.f, ptd = 0.f, lp = 0.f;
                #pragma unroll
                for (int br = 0; br < 2; ++br) {
                    int b  = 2 * lane + br;
                    int ct = (b < 3) ? 0 : 1;
                    int cc = ((b < 3) ? b : b - 3) * 5;
                    float o0v = S[(cc + 0) * 4 + 2 * ct] + bo0;
                    float o0t = S[(cc + 1) * 4 + 2 * ct];
                    float o0p = S[(cc + 2) * 4 + 2 * ct];
                    float o0q = S[(cc + 3) * 4 + 2 * ct];
                    float o0L = S[(cc + 4) * 4 + 2 * ct];
                    float o1v = S[(cc + 0) * 4 + 2 * ct + 1] + bo1;
                    float T = tanh_fast(o0v);
                    float p = fmaf(0.5f, T, 0.5f);
                    float s = 0.5f * fmaf(-T, T, 1.f);
                    float lap = s * o0L - 2.f * T * s * fmaf(o0p, o0p, o0q * o0q);
                    float cl = KCOEF * fmaf(0.5f, tanh_fast(o1v), 0.5f);
                    float cb = fmaf(DCOEF, (-2.f * p + 3.f) * p * p, cl);
                    ph  += 0.5f * p;
                    cv  += 0.5f * cb;
                    ptd += 0.5f * s * o0t;
                    lp  += 0.5f * lap;
                }
                float hph = (-2.f * ph + 3.f) * ph * ph;
                float dh  = 6.f * ph * (1.f - ph);
                float dg  = ((4.f * ph - 6.f) * ph + 2.f) * ph;
                float ac  = ptd
                          - 2.f * ((cv - hph * DCOEF - CLE_C) * DCOEF) * dh
                          + dg
                          - 0.01f * lp;
                out[pt] = ac;
            }
        }
    }
}

extern "C" void kernel_launch(void* const* d_in, const int* in_sizes, int n_in,
                              void* d_out, int out_size, void* d_ws, size_t ws_size,
                              hipStream_t stream) {
    const float* x    = (const float*)d_in[0];
    const float* t    = (const float*)d_in[1];
    const float* B    = (const float*)d_in[2];
    const float* Wh   = (const float*)d_in[3];
    const float* bh   = (const float*)d_in[4];
    const float* Wout = (const float*)d_in[5];
    const float* bout = (const float*)d_in[6];
    float* out = (float*)d_out;
    uint32* Wp = (uint32*)d_ws;                       // 128 KB scratch

    const int npts = in_sizes[0] / 2;
    hipLaunchKernelGGL(pinn_prep, dim3(128), dim3(256), 0, stream, Wh, Wp);
    const int nb = (npts + PTS_PER_BLOCK - 1) / PTS_PER_BLOCK;
    hipLaunchKernelGGL(pinn_mfma, dim3(nb), dim3(192), 0, stream,
                       x, t, B, Wp, bh, Wout, bout, out, npts);
}

// Round 8
// 138.512 us; speedup vs baseline: 1.0501x; 1.0501x over previous
//
#include <hip/hip_runtime.h>
#include <math.h>

#define PTS_PER_BLOCK 9
#define NPTS_PER_WAVE 3
#define WAVES_PER_BLOCK 3

typedef _Float16 h8 __attribute__((ext_vector_type(8)));
typedef _Float16 h2 __attribute__((ext_vector_type(2)));
typedef __fp16   fp16x2 __attribute__((ext_vector_type(2)));
typedef float    f4 __attribute__((ext_vector_type(4)));
typedef unsigned int uint32;

// cfg constants
#define CSE_C 0.5f
#define CLE_C 0.00574f
#define DCOEF (CSE_C - CLE_C)          // 0.49426
#define KCOEF (1.0f - CSE_C + CLE_C)   // 0.50574

__device__ __forceinline__ float tanh_fast(float xx) {
    float e = __expf(2.0f * xx);
    float r = __builtin_amdgcn_rcpf(e + 1.0f);
    return fmaf(-2.0f, r, 1.0f);
}
__device__ __forceinline__ unsigned short f2h(float a) {
    union { _Float16 h; unsigned short u; } ua; ua.h = (_Float16)a; return ua.u;
}
__device__ __forceinline__ h2 pkrtz(float a, float b) {
    union { fp16x2 f; h2 h; } x; x.f = __builtin_amdgcn_cvt_pkrtz(a, b); return x.h;
}
__device__ __forceinline__ uint32 pk2h(float a, float b) {
    union { h2 h; uint32 u; } x; x.h = pkrtz(a, b); return x.u;
}
__device__ __forceinline__ h8 h8_from4(uint32 a, uint32 b, uint32 c, uint32 d) {
    union { uint32 u[4]; h8 v; } x; x.u[0] = a; x.u[1] = b; x.u[2] = c; x.u[3] = d;
    return x.v;
}

// ---------------------------------------------------------------------------
// Prep: Wh (4,128,128 f32) -> A-fragment-ordered f16 W^T tiles, [L][jo][kt]
// A-frag (16x16x32 f16): lane holds row m=lane&15, k=(lane>>4)*8+e.
//   Wp[ ((L*8+jo)*4+kt)*256 + lane*4 + d ] packs (k=kt*32+(lane>>4)*8+2d, k+1)
// value = W^T[m,k] = Wh[L][k][jout=jo*16+m]
// ---------------------------------------------------------------------------
extern "C" __global__ __launch_bounds__(256)
void pinn_prep(const float* __restrict__ Wh, uint32* __restrict__ Wp)
{
    int gid  = blockIdx.x * 256 + threadIdx.x;       // 0..32767
    int d    = gid & 3;
    int lane = (gid >> 2) & 63;
    int kt   = (gid >> 8) & 3;
    int jo   = (gid >> 10) & 7;
    int L    = gid >> 13;
    int j    = kt * 32 + (lane >> 4) * 8 + 2 * d;
    int jout = jo * 16 + (lane & 15);
    float w0 = Wh[(L * 128 + j) * 128 + jout];
    float w1 = Wh[(L * 128 + j + 1) * 128 + jout];
    Wp[gid] = pk2h(w0, w1);
}

// ---------------------------------------------------------------------------
// Main: barrier-free. One wave = 3 points = 6 branch-points (bp), 5 channels:
//   ch: 0=value 1=d/dt 2=d/dx0 3=d/dx1 4=laplacian
// Per wave, 32 MFMA columns = 2 col-tiles x (3bp x 5ch + pad).
// H per wave in LDS [32][136] f16 (linear, R6 layout); W streamed from L2,
// 2-deep in-loop prefetch + cross-layer prefetch hidden under phase B /
// embed. Native v_sin/v_cos (revolutions) in the embedding.
// ---------------------------------------------------------------------------
extern "C" __global__ __launch_bounds__(192, 4)
void pinn_mfma(const float* __restrict__ x, const float* __restrict__ t,
               const float* __restrict__ B, const uint32* __restrict__ Wp,
               const float* __restrict__ bh, const float* __restrict__ Wout,
               const float* __restrict__ bout, float* __restrict__ out, int npts)
{
    __shared__ __align__(16) unsigned short H[WAVES_PER_BLOCK][32][136]; // 26112 B

    const int tid  = threadIdx.x;
    const int lane = tid & 63;
    const int wv   = tid >> 6;
    const int c    = lane & 15;
    const int g    = lane >> 4;
    const int base_pt = blockIdx.x * PTS_PER_BLOCK + wv * NPTS_PER_WAVE;

    unsigned short* Hb = &H[wv][0][0];

    // W tiles double-buffered; L0's first two tiles issued before the embed
    // so their L2 latency hides under the embedding math.
    uint4 wt[2][4];
    {
        const uint4* W0 = (const uint4*)Wp;
        #pragma unroll
        for (int kt = 0; kt < 4; ++kt) wt[0][kt] = W0[kt * 64 + lane];
        #pragma unroll
        for (int kt = 0; kt < 4; ++kt) wt[1][kt] = W0[(4 + kt) * 64 + lane];
    }

    // ---------------- embedding (writes layer-0 H) ----------------
    {
        const float TWO_PI = 6.28318530717958647692f;
        const float Br0 = B[lane], Br1 = B[64 + lane], Br2 = B[128 + lane];
        const float b0 = TWO_PI * Br0, b1 = TWO_PI * Br1, b2 = TWO_PI * Br2;
        const float bsq = fmaf(b0, b0, b1 * b1);
        #pragma unroll
        for (int pl = 0; pl < 3; ++pl) {
            int pt = base_pt + pl; if (pt > npts - 1) pt = npts - 1;
            const float2 xx = *(const float2*)&x[2 * pt];
            const float tt = t[pt];
            const float uc = fmaf(xx.y, Br1, tt * Br2);   // x1*B1 + t*B2 (revolutions)
            const float ux = xx.x * Br0;
            #pragma unroll
            for (int mir = 0; mir < 2; ++mir) {
                float u = mir ? (uc - ux) : (uc + ux);
                float r = u - floorf(u);
                float sf = __builtin_amdgcn_sinf(r);      // sin(2*pi*u)
                float cf = __builtin_amdgcn_cosf(r);      // cos(2*pi*u)
                const int b  = pl * 2 + mir;
                const int rs = (b < 3) ? 5 * b : 16 + 5 * (b - 3);
                Hb[(rs + 0) * 136 + lane] = f2h(sf);
                Hb[(rs + 1) * 136 + lane] = f2h(cf * b2);
                Hb[(rs + 2) * 136 + lane] = f2h(cf * b0);
                Hb[(rs + 3) * 136 + lane] = f2h(cf * b1);
                Hb[(rs + 4) * 136 + lane] = f2h(-sf * bsq);
                Hb[(rs + 0) * 136 + 64 + lane] = f2h(cf);
                Hb[(rs + 1) * 136 + 64 + lane] = f2h(-sf * b2);
                Hb[(rs + 2) * 136 + 64 + lane] = f2h(-sf * b0);
                Hb[(rs + 3) * 136 + 64 + lane] = f2h(-sf * b1);
                Hb[(rs + 4) * 136 + 64 + lane] = f2h(-cf * bsq);
            }
        }
    }
    asm volatile("s_waitcnt lgkmcnt(0)" ::: "memory");

    // ---------------- hidden layers ----------------
    for (int L = 0; L < 4; ++L) {
        // B-fragments: col = own ch-row, k = j (contiguous 8)
        h8 bf[2][4];
        #pragma unroll
        for (int ct = 0; ct < 2; ++ct)
            #pragma unroll
            for (int kt = 0; kt < 4; ++kt)
                bf[ct][kt] = *(const h8*)&Hb[(ct * 16 + c) * 136 + kt * 32 + g * 8];

        const uint4* WL = (const uint4*)Wp + (size_t)L * 2048;   // layer base
        const uint4* WN = WL + 2048;                              // next layer

        #pragma unroll
        for (int jo = 0; jo < 8; ++jo) {
            const int cur = jo & 1;
            f4 a0 = {0.f, 0.f, 0.f, 0.f}, a1 = {0.f, 0.f, 0.f, 0.f};
            #pragma unroll
            for (int kt = 0; kt < 4; ++kt) {
                union { uint4 u; h8 v; } af;
                af.u = wt[cur][kt];
                a0 = __builtin_amdgcn_mfma_f32_16x16x32_f16(af.v, bf[0][kt], a0, 0, 0, 0);
                a1 = __builtin_amdgcn_mfma_f32_16x16x32_f16(af.v, bf[1][kt], a1, 0, 0, 0);
            }
            // refill the consumed buffer: jo+2 of this layer, or tiles 0/1 of
            // the next layer (issued here so phase B hides their latency)
            if (jo < 6) {
                #pragma unroll
                for (int kt = 0; kt < 4; ++kt)
                    wt[cur][kt] = WL[((jo + 2) * 4 + kt) * 64 + lane];
            } else if (L < 3) {
                #pragma unroll
                for (int kt = 0; kt < 4; ++kt)
                    wt[cur][kt] = WN[((jo - 6) * 4 + kt) * 64 + lane];
            }
            // phase A: raw pre-activations (C layout: row=jo*16+g*4+r, col=c)
            union { h2 h[2]; uint2 u; } w0, w1;
            w0.h[0] = pkrtz(a0[0], a0[1]); w0.h[1] = pkrtz(a0[2], a0[3]);
            w1.h[0] = pkrtz(a1[0], a1[1]); w1.h[1] = pkrtz(a1[2], a1[3]);
            *(uint2*)&Hb[(0  + c) * 136 + jo * 16 + g * 4] = w0.u;
            *(uint2*)&Hb[(16 + c) * 136 + jo * 16 + g * 4] = w1.u;
        }
        asm volatile("s_waitcnt lgkmcnt(0)" ::: "memory");

        // phase B: lane-private j-columns (j = 2*lane, 2*lane+1), packed f16.
        // Bias (value channel only) applied here.
        {
            const int jb = 2 * lane;
            const float2 bj = *(const float2*)&bh[L * 128 + jb];
            const h2 bias2 = pkrtz(bj.x, bj.y);
            const h2 m2 = {(_Float16)(-2.0f), (_Float16)(-2.0f)};
            #pragma unroll
            for (int b = 0; b < 6; ++b) {
                int rs = (b < 3) ? 5 * b : 16 + 5 * (b - 3);
                h2 vp = *(const h2*)&Hb[(rs + 0) * 136 + jb];
                h2 tp = *(const h2*)&Hb[(rs + 1) * 136 + jb];
                h2 pp = *(const h2*)&Hb[(rs + 2) * 136 + jb];
                h2 qp = *(const h2*)&Hb[(rs + 3) * 136 + jb];
                h2 Lp = *(const h2*)&Hb[(rs + 4) * 136 + jb];
                vp = vp + bias2;
                float y0 = tanh_fast((float)vp[0]);
                float y1 = tanh_fast((float)vp[1]);
                h2 yp = pkrtz(y0, y1);
                h2 sp = pkrtz(fmaf(-y0, y0, 1.f), fmaf(-y1, y1, 1.f));
                h2 qq = __builtin_elementwise_fma(pp, pp, qp * qp);
                h2 Ln = sp * __builtin_elementwise_fma(yp * m2, qq, Lp);
                *(h2*)&Hb[(rs + 0) * 136 + jb] = yp;
                *(h2*)&Hb[(rs + 1) * 136 + jb] = sp * tp;
                *(h2*)&Hb[(rs + 2) * 136 + jb] = sp * pp;
                *(h2*)&Hb[(rs + 3) * 136 + jb] = sp * qp;
                *(h2*)&Hb[(rs + 4) * 136 + jb] = Ln;
            }
        }
        asm volatile("s_waitcnt lgkmcnt(0)" ::: "memory");
    }

    // ---------------- output layer via MFMA + residual ----------------
    {
        // A = Wout^T (2x128, rows 2..15 zeroed), built in-register
        h8 afo[4];
        const int   mc  = c & 1;
        const float sel = (c < 2) ? 1.0f : 0.0f;
        #pragma unroll
        for (int kt = 0; kt < 4; ++kt) {
            uint32 u[4];
            #pragma unroll
            for (int d = 0; d < 4; ++d) {
                int k = kt * 32 + g * 8 + 2 * d;
                float w0 = Wout[k * 2 + mc] * sel;
                float w1 = Wout[(k + 1) * 2 + mc] * sel;
                u[d] = pk2h(w0, w1);
            }
            afo[kt] = h8_from4(u[0], u[1], u[2], u[3]);
        }
        // B = final H (same fragment pattern as hidden layers)
        h8 bfo[2][4];
        #pragma unroll
        for (int ct = 0; ct < 2; ++ct)
            #pragma unroll
            for (int kt = 0; kt < 4; ++kt)
                bfo[ct][kt] = *(const h8*)&Hb[(ct * 16 + c) * 136 + kt * 32 + g * 8];

        f4 ac0 = {0.f, 0.f, 0.f, 0.f}, ac1 = {0.f, 0.f, 0.f, 0.f};
        #pragma unroll
        for (int kt = 0; kt < 4; ++kt) {
            ac0 = __builtin_amdgcn_mfma_f32_16x16x32_f16(afo[kt], bfo[0][kt], ac0, 0, 0, 0);
            ac1 = __builtin_amdgcn_mfma_f32_16x16x32_f16(afo[kt], bfo[1][kt], ac1, 0, 0, 0);
        }
        // g==0 lanes hold rows 0 (=o0) and 1 (=o1) for col c; stash to LDS
        float* S = (float*)Hb;        // 256 B scratch, H no longer needed
        if (g == 0) {
            f4 pack = {ac0[0], ac0[1], ac1[0], ac1[1]};   // o0ct0,o1ct0,o0ct1,o1ct1
            *(f4*)&S[c * 4] = pack;
        }
        asm volatile("s_waitcnt lgkmcnt(0)" ::: "memory");

        if (lane < 3) {
            int pt = base_pt + lane;
            if (pt < npts) {
                float bo0 = bout[0], bo1 = bout[1];
                float ph = 0.f, cv = 0.f, ptd = 0.f, lp = 0.f;
                #pragma unroll
                for (int br = 0; br < 2; ++br) {
                    int b  = 2 * lane + br;
                    int ct = (b < 3) ? 0 : 1;
                    int cc = ((b < 3) ? b : b - 3) * 5;
                    float o0v = S[(cc + 0) * 4 + 2 * ct] + bo0;
                    float o0t = S[(cc + 1) * 4 + 2 * ct];
                    float o0p = S[(cc + 2) * 4 + 2 * ct];
                    float o0q = S[(cc + 3) * 4 + 2 * ct];
                    float o0L = S[(cc + 4) * 4 + 2 * ct];
                    float o1v = S[(cc + 0) * 4 + 2 * ct + 1] + bo1;
                    float T = tanh_fast(o0v);
                    float p = fmaf(0.5f, T, 0.5f);
                    float s = 0.5f * fmaf(-T, T, 1.f);
                    float lap = s * o0L - 2.f * T * s * fmaf(o0p, o0p, o0q * o0q);
                    float cl = KCOEF * fmaf(0.5f, tanh_fast(o1v), 0.5f);
                    float cb = fmaf(DCOEF, (-2.f * p + 3.f) * p * p, cl);
                    ph  += 0.5f * p;
                    cv  += 0.5f * cb;
                    ptd += 0.5f * s * o0t;
                    lp  += 0.5f * lap;
                }
                float hph = (-2.f * ph + 3.f) * ph * ph;
                float dh  = 6.f * ph * (1.f - ph);
                float dg  = ((4.f * ph - 6.f) * ph + 2.f) * ph;
                float ac  = ptd
                          - 2.f * ((cv - hph * DCOEF - CLE_C) * DCOEF) * dh
                          + dg
                          - 0.01f * lp;
                out[pt] = ac;
            }
        }
    }
}

extern "C" void kernel_launch(void* const* d_in, const int* in_sizes, int n_in,
                              void* d_out, int out_size, void* d_ws, size_t ws_size,
                              hipStream_t stream) {
    const float* x    = (const float*)d_in[0];
    const float* t    = (const float*)d_in[1];
    const float* B    = (const float*)d_in[2];
    const float* Wh   = (const float*)d_in[3];
    const float* bh   = (const float*)d_in[4];
    const float* Wout = (const float*)d_in[5];
    const float* bout = (const float*)d_in[6];
    float* out = (float*)d_out;
    uint32* Wp = (uint32*)d_ws;                       // 128 KB scratch

    const int npts = in_sizes[0] / 2;
    hipLaunchKernelGGL(pinn_prep, dim3(128), dim3(256), 0, stream, Wh, Wp);
    const int nb = (npts + PTS_PER_BLOCK - 1) / PTS_PER_BLOCK;
    hipLaunchKernelGGL(pinn_mfma, dim3(nb), dim3(192), 0, stream,
                       x, t, B, Wp, bh, Wout, bout, out, npts);
}

// Round 9
// 137.471 us; speedup vs baseline: 1.0580x; 1.0076x over previous
//
#include <hip/hip_runtime.h>
#include <math.h>

#define PTS_PER_BLOCK 6
#define NPTS_PER_WAVE 3
#define WAVES_PER_BLOCK 2

typedef _Float16 h8 __attribute__((ext_vector_type(8)));
typedef _Float16 h2 __attribute__((ext_vector_type(2)));
typedef __fp16   fp16x2 __attribute__((ext_vector_type(2)));
typedef float    f4 __attribute__((ext_vector_type(4)));
typedef unsigned int uint32;

// cfg constants
#define CSE_C 0.5f
#define CLE_C 0.00574f
#define DCOEF (CSE_C - CLE_C)          // 0.49426
#define KCOEF (1.0f - CSE_C + CLE_C)   // 0.50574

__device__ __forceinline__ float tanh_fast(float xx) {
    float e = __expf(2.0f * xx);
    float r = __builtin_amdgcn_rcpf(e + 1.0f);
    return fmaf(-2.0f, r, 1.0f);
}
__device__ __forceinline__ unsigned short f2h(float a) {
    union { _Float16 h; unsigned short u; } ua; ua.h = (_Float16)a; return ua.u;
}
__device__ __forceinline__ h2 pkrtz(float a, float b) {
    union { fp16x2 f; h2 h; } x; x.f = __builtin_amdgcn_cvt_pkrtz(a, b); return x.h;
}
__device__ __forceinline__ uint32 pk2h(float a, float b) {
    union { h2 h; uint32 u; } x; x.h = pkrtz(a, b); return x.u;
}
__device__ __forceinline__ h8 h8_from4(uint32 a, uint32 b, uint32 c, uint32 d) {
    union { uint32 u[4]; h8 v; } x; x.u[0] = a; x.u[1] = b; x.u[2] = c; x.u[3] = d;
    return x.v;
}

// ---------------------------------------------------------------------------
// Prep: Wh (4,128,128 f32) -> A-fragment-ordered f16 W^T tiles, [L][jo][kt]
// A-frag (16x16x32 f16): lane holds row m=lane&15, k=(lane>>4)*8+e.
//   Wp[ ((L*8+jo)*4+kt)*256 + lane*4 + d ] packs (k=kt*32+(lane>>4)*8+2d, k+1)
// value = W^T[m,k] = Wh[L][k][jout=jo*16+m]
// ---------------------------------------------------------------------------
extern "C" __global__ __launch_bounds__(256)
void pinn_prep(const float* __restrict__ Wh, uint32* __restrict__ Wp)
{
    int gid  = blockIdx.x * 256 + threadIdx.x;       // 0..32767
    int d    = gid & 3;
    int lane = (gid >> 2) & 63;
    int kt   = (gid >> 8) & 3;
    int jo   = (gid >> 10) & 7;
    int L    = gid >> 13;
    int j    = kt * 32 + (lane >> 4) * 8 + 2 * d;
    int jout = jo * 16 + (lane & 15);
    float w0 = Wh[(L * 128 + j) * 128 + jout];
    float w1 = Wh[(L * 128 + j + 1) * 128 + jout];
    Wp[gid] = pk2h(w0, w1);
}

// ---------------------------------------------------------------------------
// Main: barrier-free. One wave = 3 points = 6 branch-points (bp), 5 channels:
//   ch: 0=value 1=d/dt 2=d/dx0 3=d/dx1 4=laplacian
// Per wave, 32 MFMA columns = 2 col-tiles x (3bp x 5ch + pad).
// H per wave in LDS [32][136] f16; W streamed from L2, 2-deep prefetch +
// cross-layer prefetch. 2 waves/block (17.4 KB LDS) to raise per-CU wave
// residency -> inter-wave MFMA/VALU overlap.
// ---------------------------------------------------------------------------
extern "C" __global__ __launch_bounds__(128, 4)
void pinn_mfma(const float* __restrict__ x, const float* __restrict__ t,
               const float* __restrict__ B, const uint32* __restrict__ Wp,
               const float* __restrict__ bh, const float* __restrict__ Wout,
               const float* __restrict__ bout, float* __restrict__ out, int npts)
{
    __shared__ __align__(16) unsigned short H[WAVES_PER_BLOCK][32][136]; // 17408 B

    const int tid  = threadIdx.x;
    const int lane = tid & 63;
    const int wv   = tid >> 6;
    const int c    = lane & 15;
    const int g    = lane >> 4;
    const int base_pt = blockIdx.x * PTS_PER_BLOCK + wv * NPTS_PER_WAVE;

    unsigned short* Hb = &H[wv][0][0];

    // W tiles double-buffered; L0's first two tiles issued before the embed
    // so their L2 latency hides under the embedding math.
    uint4 wt[2][4];
    {
        const uint4* W0 = (const uint4*)Wp;
        #pragma unroll
        for (int kt = 0; kt < 4; ++kt) wt[0][kt] = W0[kt * 64 + lane];
        #pragma unroll
        for (int kt = 0; kt < 4; ++kt) wt[1][kt] = W0[(4 + kt) * 64 + lane];
    }

    // ---------------- embedding (writes layer-0 H) ----------------
    {
        const float TWO_PI = 6.28318530717958647692f;
        const float Br0 = B[lane], Br1 = B[64 + lane], Br2 = B[128 + lane];
        const float b0 = TWO_PI * Br0, b1 = TWO_PI * Br1, b2 = TWO_PI * Br2;
        const float bsq = fmaf(b0, b0, b1 * b1);
        #pragma unroll
        for (int pl = 0; pl < 3; ++pl) {
            int pt = base_pt + pl; if (pt > npts - 1) pt = npts - 1;
            const float2 xx = *(const float2*)&x[2 * pt];
            const float tt = t[pt];
            const float uc = fmaf(xx.y, Br1, tt * Br2);   // x1*B1 + t*B2 (revolutions)
            const float ux = xx.x * Br0;
            #pragma unroll
            for (int mir = 0; mir < 2; ++mir) {
                float u = mir ? (uc - ux) : (uc + ux);
                float r = u - floorf(u);
                float sf = __builtin_amdgcn_sinf(r);      // sin(2*pi*u)
                float cf = __builtin_amdgcn_cosf(r);      // cos(2*pi*u)
                const int b  = pl * 2 + mir;
                const int rs = (b < 3) ? 5 * b : 16 + 5 * (b - 3);
                Hb[(rs + 0) * 136 + lane] = f2h(sf);
                Hb[(rs + 1) * 136 + lane] = f2h(cf * b2);
                Hb[(rs + 2) * 136 + lane] = f2h(cf * b0);
                Hb[(rs + 3) * 136 + lane] = f2h(cf * b1);
                Hb[(rs + 4) * 136 + lane] = f2h(-sf * bsq);
                Hb[(rs + 0) * 136 + 64 + lane] = f2h(cf);
                Hb[(rs + 1) * 136 + 64 + lane] = f2h(-sf * b2);
                Hb[(rs + 2) * 136 + 64 + lane] = f2h(-sf * b0);
                Hb[(rs + 3) * 136 + 64 + lane] = f2h(-sf * b1);
                Hb[(rs + 4) * 136 + 64 + lane] = f2h(-cf * bsq);
            }
        }
    }
    asm volatile("s_waitcnt lgkmcnt(0)" ::: "memory");

    // ---------------- hidden layers ----------------
    for (int L = 0; L < 4; ++L) {
        // B-fragments: col = own ch-row, k = j (contiguous 8)
        h8 bf[2][4];
        #pragma unroll
        for (int ct = 0; ct < 2; ++ct)
            #pragma unroll
            for (int kt = 0; kt < 4; ++kt)
                bf[ct][kt] = *(const h8*)&Hb[(ct * 16 + c) * 136 + kt * 32 + g * 8];

        const uint4* WL = (const uint4*)Wp + (size_t)L * 2048;   // layer base
        const uint4* WN = WL + 2048;                              // next layer

        #pragma unroll
        for (int jo = 0; jo < 8; ++jo) {
            const int cur = jo & 1;
            f4 a0 = {0.f, 0.f, 0.f, 0.f}, a1 = {0.f, 0.f, 0.f, 0.f};
            #pragma unroll
            for (int kt = 0; kt < 4; ++kt) {
                union { uint4 u; h8 v; } af;
                af.u = wt[cur][kt];
                a0 = __builtin_amdgcn_mfma_f32_16x16x32_f16(af.v, bf[0][kt], a0, 0, 0, 0);
                a1 = __builtin_amdgcn_mfma_f32_16x16x32_f16(af.v, bf[1][kt], a1, 0, 0, 0);
            }
            // refill the consumed buffer: jo+2 of this layer, or tiles 0/1 of
            // the next layer (issued here so phase B hides their latency)
            if (jo < 6) {
                #pragma unroll
                for (int kt = 0; kt < 4; ++kt)
                    wt[cur][kt] = WL[((jo + 2) * 4 + kt) * 64 + lane];
            } else if (L < 3) {
                #pragma unroll
                for (int kt = 0; kt < 4; ++kt)
                    wt[cur][kt] = WN[((jo - 6) * 4 + kt) * 64 + lane];
            }
            // phase A: raw pre-activations (C layout: row=jo*16+g*4+r, col=c)
            union { h2 h[2]; uint2 u; } w0, w1;
            w0.h[0] = pkrtz(a0[0], a0[1]); w0.h[1] = pkrtz(a0[2], a0[3]);
            w1.h[0] = pkrtz(a1[0], a1[1]); w1.h[1] = pkrtz(a1[2], a1[3]);
            *(uint2*)&Hb[(0  + c) * 136 + jo * 16 + g * 4] = w0.u;
            *(uint2*)&Hb[(16 + c) * 136 + jo * 16 + g * 4] = w1.u;
        }
        asm volatile("s_waitcnt lgkmcnt(0)" ::: "memory");

        // phase B: lane-private j-columns (j = 2*lane, 2*lane+1), packed f16.
        // Bias (value channel only) applied here.
        {
            const int jb = 2 * lane;
            const float2 bj = *(const float2*)&bh[L * 128 + jb];
            const h2 bias2 = pkrtz(bj.x, bj.y);
            const h2 m2 = {(_Float16)(-2.0f), (_Float16)(-2.0f)};
            #pragma unroll
            for (int b = 0; b < 6; ++b) {
                int rs = (b < 3) ? 5 * b : 16 + 5 * (b - 3);
                h2 vp = *(const h2*)&Hb[(rs + 0) * 136 + jb];
                h2 tp = *(const h2*)&Hb[(rs + 1) * 136 + jb];
                h2 pp = *(const h2*)&Hb[(rs + 2) * 136 + jb];
                h2 qp = *(const h2*)&Hb[(rs + 3) * 136 + jb];
                h2 Lp = *(const h2*)&Hb[(rs + 4) * 136 + jb];
                vp = vp + bias2;
                float y0 = tanh_fast((float)vp[0]);
                float y1 = tanh_fast((float)vp[1]);
                h2 yp = pkrtz(y0, y1);
                h2 sp = pkrtz(fmaf(-y0, y0, 1.f), fmaf(-y1, y1, 1.f));
                h2 qq = __builtin_elementwise_fma(pp, pp, qp * qp);
                h2 Ln = sp * __builtin_elementwise_fma(yp * m2, qq, Lp);
                *(h2*)&Hb[(rs + 0) * 136 + jb] = yp;
                *(h2*)&Hb[(rs + 1) * 136 + jb] = sp * tp;
                *(h2*)&Hb[(rs + 2) * 136 + jb] = sp * pp;
                *(h2*)&Hb[(rs + 3) * 136 + jb] = sp * qp;
                *(h2*)&Hb[(rs + 4) * 136 + jb] = Ln;
            }
        }
        asm volatile("s_waitcnt lgkmcnt(0)" ::: "memory");
    }

    // ---------------- output layer via MFMA + residual ----------------
    {
        // A = Wout^T (2x128, rows 2..15 zeroed), built in-register
        h8 afo[4];
        const int   mc  = c & 1;
        const float sel = (c < 2) ? 1.0f : 0.0f;
        #pragma unroll
        for (int kt = 0; kt < 4; ++kt) {
            uint32 u[4];
            #pragma unroll
            for (int d = 0; d < 4; ++d) {
                int k = kt * 32 + g * 8 + 2 * d;
                float w0 = Wout[k * 2 + mc] * sel;
                float w1 = Wout[(k + 1) * 2 + mc] * sel;
                u[d] = pk2h(w0, w1);
            }
            afo[kt] = h8_from4(u[0], u[1], u[2], u[3]);
        }
        // B = final H (same fragment pattern as hidden layers)
        h8 bfo[2][4];
        #pragma unroll
        for (int ct = 0; ct < 2; ++ct)
            #pragma unroll
            for (int kt = 0; kt < 4; ++kt)
                bfo[ct][kt] = *(const h8*)&Hb[(ct * 16 + c) * 136 + kt * 32 + g * 8];

        f4 ac0 = {0.f, 0.f, 0.f, 0.f}, ac1 = {0.f, 0.f, 0.f, 0.f};
        #pragma unroll
        for (int kt = 0; kt < 4; ++kt) {
            ac0 = __builtin_amdgcn_mfma_f32_16x16x32_f16(afo[kt], bfo[0][kt], ac0, 0, 0, 0);
            ac1 = __builtin_amdgcn_mfma_f32_16x16x32_f16(afo[kt], bfo[1][kt], ac1, 0, 0, 0);
        }
        // g==0 lanes hold rows 0 (=o0) and 1 (=o1) for col c; stash to LDS
        float* S = (float*)Hb;        // 256 B scratch, H no longer needed
        if (g == 0) {
            f4 pack = {ac0[0], ac0[1], ac1[0], ac1[1]};   // o0ct0,o1ct0,o0ct1,o1ct1
            *(f4*)&S[c * 4] = pack;
        }
        asm volatile("s_waitcnt lgkmcnt(0)" ::: "memory");

        if (lane < 3) {
            int pt = base_pt + lane;
            if (pt < npts) {
                float bo0 = bout[0], bo1 = bout[1];
                float ph = 0.f, cv = 0.f, ptd = 0.f, lp = 0.f;
                #pragma unroll
                for (int br = 0; br < 2; ++br) {
                    int b  = 2 * lane + br;
                    int ct = (b < 3) ? 0 : 1;
                    int cc = ((b < 3) ? b : b - 3) * 5;
                    float o0v = S[(cc + 0) * 4 + 2 * ct] + bo0;
                    float o0t = S[(cc + 1) * 4 + 2 * ct];
                    float o0p = S[(cc + 2) * 4 + 2 * ct];
                    float o0q = S[(cc + 3) * 4 + 2 * ct];
                    float o0L = S[(cc + 4) * 4 + 2 * ct];
                    float o1v = S[(cc + 0) * 4 + 2 * ct + 1] + bo1;
                    float T = tanh_fast(o0v);
                    float p = fmaf(0.5f, T, 0.5f);
                    float s = 0.5f * fmaf(-T, T, 1.f);
                    float lap = s * o0L - 2.f * T * s * fmaf(o0p, o0p, o0q * o0q);
                    float cl = KCOEF * fmaf(0.5f, tanh_fast(o1v), 0.5f);
                    float cb = fmaf(DCOEF, (-2.f * p + 3.f) * p * p, cl);
                    ph  += 0.5f * p;
                    cv  += 0.5f * cb;
                    ptd += 0.5f * s * o0t;
                    lp  += 0.5f * lap;
                }
                float hph = (-2.f * ph + 3.f) * ph * ph;
                float dh  = 6.f * ph * (1.f - ph);
                float dg  = ((4.f * ph - 6.f) * ph + 2.f) * ph;
                float ac  = ptd
                          - 2.f * ((cv - hph * DCOEF - CLE_C) * DCOEF) * dh
                          + dg
                          - 0.01f * lp;
                out[pt] = ac;
            }
        }
    }
}

extern "C" void kernel_launch(void* const* d_in, const int* in_sizes, int n_in,
                              void* d_out, int out_size, void* d_ws, size_t ws_size,
                              hipStream_t stream) {
    const float* x    = (const float*)d_in[0];
    const float* t    = (const float*)d_in[1];
    const float* B    = (const float*)d_in[2];
    const float* Wh   = (const float*)d_in[3];
    const float* bh   = (const float*)d_in[4];
    const float* Wout = (const float*)d_in[5];
    const float* bout = (const float*)d_in[6];
    float* out = (float*)d_out;
    uint32* Wp = (uint32*)d_ws;                       // 128 KB scratch

    const int npts = in_sizes[0] / 2;
    hipLaunchKernelGGL(pinn_prep, dim3(128), dim3(256), 0, stream, Wh, Wp);
    const int nb = (npts + PTS_PER_BLOCK - 1) / PTS_PER_BLOCK;
    hipLaunchKernelGGL(pinn_mfma, dim3(nb), dim3(128), 0, stream,
                       x, t, B, Wp, bh, Wout, bout, out, npts);
}

// Round 10
// 136.578 us; speedup vs baseline: 1.0649x; 1.0065x over previous
//
#include <hip/hip_runtime.h>
#include <math.h>

#define PTS_PER_BLOCK 6
#define NPTS_PER_WAVE 3
#define WAVES_PER_BLOCK 2

typedef _Float16 h8 __attribute__((ext_vector_type(8)));
typedef _Float16 h2 __attribute__((ext_vector_type(2)));
typedef __fp16   fp16x2 __attribute__((ext_vector_type(2)));
typedef float    f4 __attribute__((ext_vector_type(4)));
typedef unsigned int uint32;

// cfg constants
#define CSE_C 0.5f
#define CLE_C 0.00574f
#define DCOEF (CSE_C - CLE_C)          // 0.49426
#define KCOEF (1.0f - CSE_C + CLE_C)   // 0.50574

__device__ __forceinline__ float tanh_fast(float xx) {
    float e = __expf(2.0f * xx);
    float r = __builtin_amdgcn_rcpf(e + 1.0f);
    return fmaf(-2.0f, r, 1.0f);
}
__device__ __forceinline__ unsigned short f2h(float a) {
    union { _Float16 h; unsigned short u; } ua; ua.h = (_Float16)a; return ua.u;
}
__device__ __forceinline__ h2 pkrtz(float a, float b) {
    union { fp16x2 f; h2 h; } x; x.f = __builtin_amdgcn_cvt_pkrtz(a, b); return x.h;
}
__device__ __forceinline__ uint32 pk2h(float a, float b) {
    union { h2 h; uint32 u; } x; x.h = pkrtz(a, b); return x.u;
}
__device__ __forceinline__ h8 h8_from4(uint32 a, uint32 b, uint32 c, uint32 d) {
    union { uint32 u[4]; h8 v; } x; x.u[0] = a; x.u[1] = b; x.u[2] = c; x.u[3] = d;
    return x.v;
}

// ---------------------------------------------------------------------------
// Prep: Wh (4,128,128 f32) -> A-fragment-ordered f16 W^T tiles, [L][jo][kt]
// A-frag (16x16x32 f16): lane holds row m=lane&15, k=(lane>>4)*8+e.
//   Wp[ ((L*8+jo)*4+kt)*256 + lane*4 + d ] packs (k=kt*32+(lane>>4)*8+2d, k+1)
// value = W^T[m,k] = Wh[L][k][jout=jo*16+m]
// ---------------------------------------------------------------------------
extern "C" __global__ __launch_bounds__(256)
void pinn_prep(const float* __restrict__ Wh, uint32* __restrict__ Wp)
{
    int gid  = blockIdx.x * 256 + threadIdx.x;       // 0..32767
    int d    = gid & 3;
    int lane = (gid >> 2) & 63;
    int kt   = (gid >> 8) & 3;
    int jo   = (gid >> 10) & 7;
    int L    = gid >> 13;
    int j    = kt * 32 + (lane >> 4) * 8 + 2 * d;
    int jout = jo * 16 + (lane & 15);
    float w0 = Wh[(L * 128 + j) * 128 + jout];
    float w1 = Wh[(L * 128 + j + 1) * 128 + jout];
    Wp[gid] = pk2h(w0, w1);
}

// ---------------------------------------------------------------------------
// Main: barrier-free. One wave = 3 points = 6 branch-points (bp), 5 channels:
//   ch: 0=value 1=d/dt 2=d/dx0 3=d/dx1 4=laplacian
// Per wave, 32 MFMA columns = 2 col-tiles x (3bp x 5ch + pad).
// H per wave in LDS [32][136] f16; W streamed from L2, 2-deep prefetch +
// cross-layer prefetch. 2 waves/block (17.4 KB LDS) to raise per-CU wave
// residency -> inter-wave MFMA/VALU overlap.
// ---------------------------------------------------------------------------
extern "C" __global__ __launch_bounds__(128, 4)
void pinn_mfma(const float* __restrict__ x, const float* __restrict__ t,
               const float* __restrict__ B, const uint32* __restrict__ Wp,
               const float* __restrict__ bh, const float* __restrict__ Wout,
               const float* __restrict__ bout, float* __restrict__ out, int npts)
{
    __shared__ __align__(16) unsigned short H[WAVES_PER_BLOCK][32][136]; // 17408 B

    const int tid  = threadIdx.x;
    const int lane = tid & 63;
    const int wv   = tid >> 6;
    const int c    = lane & 15;
    const int g    = lane >> 4;
    const int base_pt = blockIdx.x * PTS_PER_BLOCK + wv * NPTS_PER_WAVE;

    unsigned short* Hb = &H[wv][0][0];

    // W tiles double-buffered; L0's first two tiles issued before the embed
    // so their L2 latency hides under the embedding math.
    uint4 wt[2][4];
    {
        const uint4* W0 = (const uint4*)Wp;
        #pragma unroll
        for (int kt = 0; kt < 4; ++kt) wt[0][kt] = W0[kt * 64 + lane];
        #pragma unroll
        for (int kt = 0; kt < 4; ++kt) wt[1][kt] = W0[(4 + kt) * 64 + lane];
    }

    // ---------------- embedding (writes layer-0 H) ----------------
    {
        const float TWO_PI = 6.28318530717958647692f;
        const float Br0 = B[lane], Br1 = B[64 + lane], Br2 = B[128 + lane];
        const float b0 = TWO_PI * Br0, b1 = TWO_PI * Br1, b2 = TWO_PI * Br2;
        const float bsq = fmaf(b0, b0, b1 * b1);
        #pragma unroll
        for (int pl = 0; pl < 3; ++pl) {
            int pt = base_pt + pl; if (pt > npts - 1) pt = npts - 1;
            const float2 xx = *(const float2*)&x[2 * pt];
            const float tt = t[pt];
            const float uc = fmaf(xx.y, Br1, tt * Br2);   // x1*B1 + t*B2 (revolutions)
            const float ux = xx.x * Br0;
            #pragma unroll
            for (int mir = 0; mir < 2; ++mir) {
                float u = mir ? (uc - ux) : (uc + ux);
                float r = u - floorf(u);
                float sf = __builtin_amdgcn_sinf(r);      // sin(2*pi*u)
                float cf = __builtin_amdgcn_cosf(r);      // cos(2*pi*u)
                const int b  = pl * 2 + mir;
                const int rs = (b < 3) ? 5 * b : 16 + 5 * (b - 3);
                Hb[(rs + 0) * 136 + lane] = f2h(sf);
                Hb[(rs + 1) * 136 + lane] = f2h(cf * b2);
                Hb[(rs + 2) * 136 + lane] = f2h(cf * b0);
                Hb[(rs + 3) * 136 + lane] = f2h(cf * b1);
                Hb[(rs + 4) * 136 + lane] = f2h(-sf * bsq);
                Hb[(rs + 0) * 136 + 64 + lane] = f2h(cf);
                Hb[(rs + 1) * 136 + 64 + lane] = f2h(-sf * b2);
                Hb[(rs + 2) * 136 + 64 + lane] = f2h(-sf * b0);
                Hb[(rs + 3) * 136 + 64 + lane] = f2h(-sf * b1);
                Hb[(rs + 4) * 136 + 64 + lane] = f2h(-cf * bsq);
            }
        }
    }
    asm volatile("s_waitcnt lgkmcnt(0)" ::: "memory");

    // ---------------- hidden layers ----------------
    for (int L = 0; L < 4; ++L) {
        // B-fragments: col = own ch-row, k = j (contiguous 8)
        h8 bf[2][4];
        #pragma unroll
        for (int ct = 0; ct < 2; ++ct)
            #pragma unroll
            for (int kt = 0; kt < 4; ++kt)
                bf[ct][kt] = *(const h8*)&Hb[(ct * 16 + c) * 136 + kt * 32 + g * 8];

        const uint4* WL = (const uint4*)Wp + (size_t)L * 2048;   // layer base
        const uint4* WN = WL + 2048;                              // next layer

        #pragma unroll
        for (int jo = 0; jo < 8; ++jo) {
            const int cur = jo & 1;
            f4 a0 = {0.f, 0.f, 0.f, 0.f}, a1 = {0.f, 0.f, 0.f, 0.f};
            #pragma unroll
            for (int kt = 0; kt < 4; ++kt) {
                union { uint4 u; h8 v; } af;
                af.u = wt[cur][kt];
                a0 = __builtin_amdgcn_mfma_f32_16x16x32_f16(af.v, bf[0][kt], a0, 0, 0, 0);
                a1 = __builtin_amdgcn_mfma_f32_16x16x32_f16(af.v, bf[1][kt], a1, 0, 0, 0);
            }
            // refill the consumed buffer: jo+2 of this layer, or tiles 0/1 of
            // the next layer (issued here so phase B hides their latency)
            if (jo < 6) {
                #pragma unroll
                for (int kt = 0; kt < 4; ++kt)
                    wt[cur][kt] = WL[((jo + 2) * 4 + kt) * 64 + lane];
            } else if (L < 3) {
                #pragma unroll
                for (int kt = 0; kt < 4; ++kt)
                    wt[cur][kt] = WN[((jo - 6) * 4 + kt) * 64 + lane];
            }
            // phase A: raw pre-activations (C layout: row=jo*16+g*4+r, col=c)
            union { h2 h[2]; uint2 u; } w0, w1;
            w0.h[0] = pkrtz(a0[0], a0[1]); w0.h[1] = pkrtz(a0[2], a0[3]);
            w1.h[0] = pkrtz(a1[0], a1[1]); w1.h[1] = pkrtz(a1[2], a1[3]);
            *(uint2*)&Hb[(0  + c) * 136 + jo * 16 + g * 4] = w0.u;
            *(uint2*)&Hb[(16 + c) * 136 + jo * 16 + g * 4] = w1.u;
        }
        asm volatile("s_waitcnt lgkmcnt(0)" ::: "memory");

        // phase B: lane-private j-columns (j = 2*lane, 2*lane+1), packed f16.
        // Bias (value channel only) applied here.
        {
            const int jb = 2 * lane;
            const float2 bj = *(const float2*)&bh[L * 128 + jb];
            const h2 bias2 = pkrtz(bj.x, bj.y);
            const h2 m2 = {(_Float16)(-2.0f), (_Float16)(-2.0f)};
            #pragma unroll
            for (int b = 0; b < 6; ++b) {
                int rs = (b < 3) ? 5 * b : 16 + 5 * (b - 3);
                h2 vp = *(const h2*)&Hb[(rs + 0) * 136 + jb];
                h2 tp = *(const h2*)&Hb[(rs + 1) * 136 + jb];
                h2 pp = *(const h2*)&Hb[(rs + 2) * 136 + jb];
                h2 qp = *(const h2*)&Hb[(rs + 3) * 136 + jb];
                h2 Lp = *(const h2*)&Hb[(rs + 4) * 136 + jb];
                vp = vp + bias2;
                float y0 = tanh_fast((float)vp[0]);
                float y1 = tanh_fast((float)vp[1]);
                h2 yp = pkrtz(y0, y1);
                h2 sp = pkrtz(fmaf(-y0, y0, 1.f), fmaf(-y1, y1, 1.f));
                h2 qq = __builtin_elementwise_fma(pp, pp, qp * qp);
                h2 Ln = sp * __builtin_elementwise_fma(yp * m2, qq, Lp);
                *(h2*)&Hb[(rs + 0) * 136 + jb] = yp;
                *(h2*)&Hb[(rs + 1) * 136 + jb] = sp * tp;
                *(h2*)&Hb[(rs + 2) * 136 + jb] = sp * pp;
                *(h2*)&Hb[(rs + 3) * 136 + jb] = sp * qp;
                *(h2*)&Hb[(rs + 4) * 136 + jb] = Ln;
            }
        }
        asm volatile("s_waitcnt lgkmcnt(0)" ::: "memory");
    }

    // ---------------- output layer via MFMA + residual ----------------
    {
        // A = Wout^T (2x128, rows 2..15 zeroed), built in-register
        h8 afo[4];
        const int   mc  = c & 1;
        const float sel = (c < 2) ? 1.0f : 0.0f;
        #pragma unroll
        for (int kt = 0; kt < 4; ++kt) {
            uint32 u[4];
            #pragma unroll
            for (int d = 0; d < 4; ++d) {
                int k = kt * 32 + g * 8 + 2 * d;
                float w0 = Wout[k * 2 + mc] * sel;
                float w1 = Wout[(k + 1) * 2 + mc] * sel;
                u[d] = pk2h(w0, w1);
            }
            afo[kt] = h8_from4(u[0], u[1], u[2], u[3]);
        }
        // B = final H (same fragment pattern as hidden layers)
        h8 bfo[2][4];
        #pragma unroll
        for (int ct = 0; ct < 2; ++ct)
            #pragma unroll
            for (int kt = 0; kt < 4; ++kt)
                bfo[ct][kt] = *(const h8*)&Hb[(ct * 16 + c) * 136 + kt * 32 + g * 8];

        f4 ac0 = {0.f, 0.f, 0.f, 0.f}, ac1 = {0.f, 0.f, 0.f, 0.f};
        #pragma unroll
        for (int kt = 0; kt < 4; ++kt) {
            ac0 = __builtin_amdgcn_mfma_f32_16x16x32_f16(afo[kt], bfo[0][kt], ac0, 0, 0, 0);
            ac1 = __builtin_amdgcn_mfma_f32_16x16x32_f16(afo[kt], bfo[1][kt], ac1, 0, 0, 0);
        }
        // g==0 lanes hold rows 0 (=o0) and 1 (=o1) for col c; stash to LDS
        float* S = (float*)Hb;        // 256 B scratch, H no longer needed
        if (g == 0) {
            f4 pack = {ac0[0], ac0[1], ac1[0], ac1[1]};   // o0ct0,o1ct0,o0ct1,o1ct1
            *(f4*)&S[c * 4] = pack;
        }
        asm volatile("s_waitcnt lgkmcnt(0)" ::: "memory");

        if (lane < 3) {
            int pt = base_pt + lane;
            if (pt < npts) {
                float bo0 = bout[0], bo1 = bout[1];
                float ph = 0.f, cv = 0.f, ptd = 0.f, lp = 0.f;
                #pragma unroll
                for (int br = 0; br < 2; ++br) {
                    int b  = 2 * lane + br;
                    int ct = (b < 3) ? 0 : 1;
                    int cc = ((b < 3) ? b : b - 3) * 5;
                    float o0v = S[(cc + 0) * 4 + 2 * ct] + bo0;
                    float o0t = S[(cc + 1) * 4 + 2 * ct];
                    float o0p = S[(cc + 2) * 4 + 2 * ct];
                    float o0q = S[(cc + 3) * 4 + 2 * ct];
                    float o0L = S[(cc + 4) * 4 + 2 * ct];
                    float o1v = S[(cc + 0) * 4 + 2 * ct + 1] + bo1;
                    float T = tanh_fast(o0v);
                    float p = fmaf(0.5f, T, 0.5f);
                    float s = 0.5f * fmaf(-T, T, 1.f);
                    float lap = s * o0L - 2.f * T * s * fmaf(o0p, o0p, o0q * o0q);
                    float cl = KCOEF * fmaf(0.5f, tanh_fast(o1v), 0.5f);
                    float cb = fmaf(DCOEF, (-2.f * p + 3.f) * p * p, cl);
                    ph  += 0.5f * p;
                    cv  += 0.5f * cb;
                    ptd += 0.5f * s * o0t;
                    lp  += 0.5f * lap;
                }
                float hph = (-2.f * ph + 3.f) * ph * ph;
                float dh  = 6.f * ph * (1.f - ph);
                float dg  = ((4.f * ph - 6.f) * ph + 2.f) * ph;
                float ac  = ptd
                          - 2.f * ((cv - hph * DCOEF - CLE_C) * DCOEF) * dh
                          + dg
                          - 0.01f * lp;
                out[pt] = ac;
            }
        }
    }
}

extern "C" void kernel_launch(void* const* d_in, const int* in_sizes, int n_in,
                              void* d_out, int out_size, void* d_ws, size_t ws_size,
                              hipStream_t stream) {
    const float* x    = (const float*)d_in[0];
    const float* t    = (const float*)d_in[1];
    const float* B    = (const float*)d_in[2];
    const float* Wh   = (const float*)d_in[3];
    const float* bh   = (const float*)d_in[4];
    const float* Wout = (const float*)d_in[5];
    const float* bout = (const float*)d_in[6];
    float* out = (float*)d_out;
    uint32* Wp = (uint32*)d_ws;                       // 128 KB scratch

    const int npts = in_sizes[0] / 2;
    hipLaunchKernelGGL(pinn_prep, dim3(128), dim3(256), 0, stream, Wh, Wp);
    const int nb = (npts + PTS_PER_BLOCK - 1) / PTS_PER_BLOCK;
    hipLaunchKernelGGL(pinn_mfma, dim3(nb), dim3(128), 0, stream,
                       x, t, B, Wp, bh, Wout, bout, out, npts);
}